// Round 1
// baseline (630.628 us; speedup 1.0000x reference)
//
#include <hip/hip_runtime.h>

// SP_Attentation: fused QKV projection + per-segment softmax attention.
// v1: fp16 split-precision MFMA (3-term QK for fp32-accurate scores), flash-style attention.

typedef _Float16 f16x8 __attribute__((ext_vector_type(8)));
typedef _Float16 f16x4 __attribute__((ext_vector_type(4)));
typedef float    f32x4 __attribute__((ext_vector_type(4)));

#define MFMA(a, b, c) __builtin_amdgcn_mfma_f32_16x16x32_f16((a), (b), (c), 0, 0, 0)

__constant__ int c_off[9] = {0, 3072, 7168, 9216, 12800, 15360, 19456, 22528, 24576};

static constexpr int NTOK = 24576;
static constexpr int C    = 256;

// ---------------- kernel A0: split weights fp32 -> fp16 hi/lo ----------------
__global__ __launch_bounds__(256) void wsplit_kernel(
    const float* __restrict__ Wq, const float* __restrict__ Wk, const float* __restrict__ Wv,
    _Float16* __restrict__ Whi, _Float16* __restrict__ Wlo)
{
  int idx = blockIdx.x * 256 + threadIdx.x;  // 3*65536 total
  int mat = idx >> 16;
  int r   = idx & 65535;
  const float* W = (mat == 0) ? Wq : (mat == 1) ? Wk : Wv;
  float v = W[r];
  _Float16 h = (_Float16)v;
  Whi[idx] = h;
  Wlo[idx] = (_Float16)(v - (float)h);
}

// ---------------- kernel A: fused QKV projection ----------------
// out = X @ W^T + b.  Q,K produced fp32-accurate (3-term split), stored as fp16 hi/lo.
// V produced with single hi-term, stored TRANSPOSED: Vt[dim][token].
__global__ __launch_bounds__(256, 2) void proj_kernel(
    const float* __restrict__ X,
    const float* __restrict__ bq, const float* __restrict__ bk, const float* __restrict__ bv,
    const _Float16* __restrict__ Whi, const _Float16* __restrict__ Wlo,
    _Float16* __restrict__ Qhi, _Float16* __restrict__ Qlo,
    _Float16* __restrict__ Khi, _Float16* __restrict__ Klo,
    _Float16* __restrict__ Vt)
{
  const int tid  = threadIdx.x;
  const int w    = tid >> 6;
  const int lane = tid & 63;
  const int l15  = lane & 15;
  const int lg   = lane >> 4;
  const int tokb = blockIdx.x * 64 + w * 16;   // wave handles 16 tokens

  // A-fragments of X, fp16 hi/lo split, kept in registers (16 tokens x 256 feats)
  // A layout: row = lane&15, k = (lane>>4)*8 + j
  f16x8 xhi[8], xlo[8];
  {
    const float* src = X + (size_t)(tokb + l15) * C + lg * 8;
    #pragma unroll
    for (int kk = 0; kk < 8; ++kk) {
      float4 a = *(const float4*)(src + kk * 32);
      float4 b = *(const float4*)(src + kk * 32 + 4);
      float v[8] = {a.x, a.y, a.z, a.w, b.x, b.y, b.z, b.w};
      f16x8 h, l;
      #pragma unroll
      for (int j = 0; j < 8; ++j) {
        _Float16 hi = (_Float16)v[j];
        h[j] = hi;
        l[j] = (_Float16)(v[j] - (float)hi);
      }
      xhi[kk] = h;
      xlo[kk] = l;
    }
  }

  #pragma unroll 1
  for (int mat = 0; mat < 3; ++mat) {
    const float* bias = (mat == 0) ? bq : (mat == 1) ? bk : bv;
    #pragma unroll 1
    for (int nb = 0; nb < 16; ++nb) {
      const int col = nb * 16 + l15;  // B layout: col = lane&15
      const _Float16* wh = Whi + (size_t)(mat * 256 + col) * C + lg * 8;
      const _Float16* wl = Wlo + (size_t)(mat * 256 + col) * C + lg * 8;
      f32x4 acc = {0.f, 0.f, 0.f, 0.f};
      if (mat < 2) {
        #pragma unroll
        for (int kk = 0; kk < 8; ++kk) {
          f16x8 bh = *(const f16x8*)(wh + kk * 32);
          f16x8 bl = *(const f16x8*)(wl + kk * 32);
          acc = MFMA(xhi[kk], bh, acc);
          acc = MFMA(xlo[kk], bh, acc);
          acc = MFMA(xhi[kk], bl, acc);
        }
      } else {
        #pragma unroll
        for (int kk = 0; kk < 8; ++kk) {
          f16x8 bh = *(const f16x8*)(wh + kk * 32);
          acc = MFMA(xhi[kk], bh, acc);
        }
      }
      const float b = bias[col];
      // C layout: row = (lane>>4)*4 + r, col = lane&15
      if (mat == 2) {
        f16x4 v4;
        #pragma unroll
        for (int r = 0; r < 4; ++r) v4[r] = (_Float16)(acc[r] + b);
        *(f16x4*)(Vt + (size_t)col * NTOK + tokb + lg * 4) = v4;
      } else {
        _Float16* Ph = (mat == 0) ? Qhi : Khi;
        _Float16* Pl = (mat == 0) ? Qlo : Klo;
        #pragma unroll
        for (int r = 0; r < 4; ++r) {
          const int tok = tokb + lg * 4 + r;
          float q = acc[r] + b;
          _Float16 qh = (_Float16)q;
          Ph[(size_t)tok * C + col] = qh;
          Pl[(size_t)tok * C + col] = (_Float16)(q - (float)qh);
        }
      }
    }
  }
}

// ---------------- kernel B: flash attention per segment ----------------
// Block = 64 Q-rows (4 waves x 16 rows). KV tiles of 32 keys staged in LDS.
__global__ __launch_bounds__(256, 2) void attn_kernel(
    const _Float16* __restrict__ Qhi, const _Float16* __restrict__ Qlo,
    const _Float16* __restrict__ Khi, const _Float16* __restrict__ Klo,
    const _Float16* __restrict__ Vt, float* __restrict__ Out)
{
  // padded rows (+8 halves = +16B) -> ds_read_b128 at 2-way conflict (free)
  __shared__ _Float16 kh_lds[32][264];
  __shared__ _Float16 kl_lds[32][264];
  __shared__ _Float16 vt_lds[256][40];
  __shared__ _Float16 p_lds[4][16][40];  // wave-private P transpose buffer

  const int tid  = threadIdx.x;
  const int w    = tid >> 6;
  const int lane = tid & 63;
  const int l15  = lane & 15;
  const int lg   = lane >> 4;

  const int qrow0 = blockIdx.x * 64;
  int seg = 0;
  #pragma unroll
  for (int i = 1; i < 8; ++i)
    if (qrow0 >= c_off[i]) seg = i;
  const int s0 = c_off[seg];
  const int n  = c_off[seg + 1] - s0;

  // Q fragments (A layout: row = lane&15), fp16 hi/lo
  f16x8 qhi[8], qlo[8];
  {
    const size_t base = (size_t)(qrow0 + w * 16 + l15) * C + lg * 8;
    #pragma unroll
    for (int kk = 0; kk < 8; ++kk) {
      qhi[kk] = *(const f16x8*)(Qhi + base + kk * 32);
      qlo[kk] = *(const f16x8*)(Qlo + base + kk * 32);
    }
  }

  f32x4 o[16];
  #pragma unroll
  for (int db = 0; db < 16; ++db) o[db] = (f32x4){0.f, 0.f, 0.f, 0.f};
  float m[4]  = {-1e30f, -1e30f, -1e30f, -1e30f};
  float ls[4] = {0.f, 0.f, 0.f, 0.f};

  for (int kv = 0; kv < n; kv += 32) {
    // ---- stage K (hi+lo) rows and Vt rows into LDS ----
    #pragma unroll
    for (int c = 0; c < 4; ++c) {
      const int idx = c * 256 + tid;
      const int key = idx >> 5, cid = idx & 31;            // 32 keys x 32 chunks(16B)
      const size_t g = (size_t)(s0 + kv + key) * C + cid * 8;
      *(f16x8*)(&kh_lds[key][cid * 8]) = *(const f16x8*)(Khi + g);
      *(f16x8*)(&kl_lds[key][cid * 8]) = *(const f16x8*)(Klo + g);
      const int dim = idx >> 2, vc = idx & 3;              // 256 dims x 4 chunks(16B)
      *(f16x8*)(&vt_lds[dim][vc * 8]) =
          *(const f16x8*)(Vt + (size_t)dim * NTOK + s0 + kv + vc * 8);
    }
    __syncthreads();

    // ---- S = Q K^T : 16 rows x 32 keys, 3-term fp16 split, fp32 acc ----
    f32x4 s0v = {0.f, 0.f, 0.f, 0.f};
    f32x4 s1v = {0.f, 0.f, 0.f, 0.f};
    #pragma unroll
    for (int kk = 0; kk < 8; ++kk) {
      const int fo = kk * 32 + lg * 8;
      f16x8 b0h = *(const f16x8*)(&kh_lds[l15][fo]);
      f16x8 b1h = *(const f16x8*)(&kh_lds[16 + l15][fo]);
      f16x8 b0l = *(const f16x8*)(&kl_lds[l15][fo]);
      f16x8 b1l = *(const f16x8*)(&kl_lds[16 + l15][fo]);
      s0v = MFMA(qhi[kk], b0h, s0v);
      s1v = MFMA(qhi[kk], b1h, s1v);
      s0v = MFMA(qlo[kk], b0h, s0v);
      s1v = MFMA(qlo[kk], b1h, s1v);
      s0v = MFMA(qhi[kk], b0l, s0v);
      s1v = MFMA(qhi[kk], b1l, s1v);
    }

    // ---- online softmax (rows of this wave: lg*4 + r) ----
    float scale[4];
    #pragma unroll
    for (int r = 0; r < 4; ++r) {
      float mx = fmaxf(s0v[r], s1v[r]);
      mx = fmaxf(mx, __shfl_xor(mx, 1));
      mx = fmaxf(mx, __shfl_xor(mx, 2));
      mx = fmaxf(mx, __shfl_xor(mx, 4));
      mx = fmaxf(mx, __shfl_xor(mx, 8));
      const float mn = fmaxf(m[r], mx);
      scale[r] = __expf(m[r] - mn);
      m[r] = mn;
      const float p0 = __expf(s0v[r] - mn);
      const float p1 = __expf(s1v[r] - mn);
      s0v[r] = p0;
      s1v[r] = p1;
      float rs = p0 + p1;
      rs += __shfl_xor(rs, 1);
      rs += __shfl_xor(rs, 2);
      rs += __shfl_xor(rs, 4);
      rs += __shfl_xor(rs, 8);
      ls[r] = ls[r] * scale[r] + rs;
    }

    // ---- P -> LDS (wave-private region; same-wave RAW ordered by lgkmcnt) ----
    #pragma unroll
    for (int r = 0; r < 4; ++r) {
      p_lds[w][lg * 4 + r][l15]      = (_Float16)s0v[r];
      p_lds[w][lg * 4 + r][16 + l15] = (_Float16)s1v[r];
    }

    // ---- rescale O ----
    #pragma unroll
    for (int db = 0; db < 16; ++db) {
      #pragma unroll
      for (int r = 0; r < 4; ++r) o[db][r] *= scale[r];
    }

    // ---- O += P V ----
    f16x8 pfrag = *(const f16x8*)(&p_lds[w][l15][lg * 8]);
    #pragma unroll
    for (int db = 0; db < 16; ++db) {
      f16x8 vfrag = *(const f16x8*)(&vt_lds[db * 16 + l15][lg * 8]);
      o[db] = MFMA(pfrag, vfrag, o[db]);
    }
    __syncthreads();
  }

  // ---- epilogue: normalize and store fp32 ----
  #pragma unroll
  for (int r = 0; r < 4; ++r) ls[r] = 1.f / ls[r];
  const int orow = qrow0 + w * 16 + lg * 4;
  #pragma unroll
  for (int db = 0; db < 16; ++db) {
    #pragma unroll
    for (int r = 0; r < 4; ++r) {
      Out[(size_t)(orow + r) * C + db * 16 + l15] = o[db][r] * ls[r];
    }
  }
}

extern "C" void kernel_launch(void* const* d_in, const int* in_sizes, int n_in,
                              void* d_out, int out_size, void* d_ws, size_t ws_size,
                              hipStream_t stream)
{
  const float* X  = (const float*)d_in[0];
  // d_in[1] = indices (unused by the reference math)
  const float* Wq = (const float*)d_in[2];
  const float* bq = (const float*)d_in[3];
  const float* Wk = (const float*)d_in[4];
  const float* bk = (const float*)d_in[5];
  const float* Wv = (const float*)d_in[6];
  const float* bv = (const float*)d_in[7];
  float* Out = (float*)d_out;

  // workspace layout (fp16): Qhi|Qlo|Khi|Klo|Vt (each NTOK*C) + Whi|Wlo (3*256*256)
  // total ~63.7 MB
  const size_t SZ = (size_t)NTOK * C;
  _Float16* ws  = (_Float16*)d_ws;
  _Float16* Qhi = ws;
  _Float16* Qlo = Qhi + SZ;
  _Float16* Khi = Qlo + SZ;
  _Float16* Klo = Khi + SZ;
  _Float16* Vt  = Klo + SZ;
  _Float16* Whi = Vt + SZ;
  _Float16* Wlo = Whi + (size_t)3 * 65536;

  hipLaunchKernelGGL(wsplit_kernel, dim3(768), dim3(256), 0, stream,
                     Wq, Wk, Wv, Whi, Wlo);
  hipLaunchKernelGGL(proj_kernel, dim3(384), dim3(256), 0, stream,
                     X, bq, bk, bv, Whi, Wlo, Qhi, Qlo, Khi, Klo, Vt);
  hipLaunchKernelGGL(attn_kernel, dim3(384), dim3(256), 0, stream,
                     Qhi, Qlo, Khi, Klo, Vt, Out);
}

// Round 4
// 567.427 us; speedup vs baseline: 1.1114x; 1.1114x over previous
//
#include <hip/hip_runtime.h>

// SP_Attentation v3: 2-term QK, async gll staging (double-K, single-V, counted
// vmcnt), source-swizzled V LDS (conflict-free PV reads), 53KB LDS -> 3 blk/CU.

typedef _Float16 f16x8 __attribute__((ext_vector_type(8)));
typedef _Float16 f16x4 __attribute__((ext_vector_type(4)));
typedef _Float16 f16x2 __attribute__((ext_vector_type(2)));
typedef float    f32x4 __attribute__((ext_vector_type(4)));
typedef unsigned int u32;

#define MFMA(a,b,c) __builtin_amdgcn_mfma_f32_16x16x32_f16((a),(b),(c),0,0,0)

typedef __attribute__((address_space(1))) const u32 gu32_t;
typedef __attribute__((address_space(3))) u32 lu32_t;

__device__ __forceinline__ void gll16(const void* g, void* l) {
  __builtin_amdgcn_global_load_lds((gu32_t*)g, (lu32_t*)l, 16, 0, 0);
}

__constant__ int c_off[9] = {0, 3072, 7168, 9216, 12800, 15360, 19456, 22528, 24576};

static constexpr int NTOK = 24576;
static constexpr int C    = 256;

// ---------------- kernel A0: split weights fp32 -> fp16 hi/lo ----------------
__global__ __launch_bounds__(256) void wsplit_kernel(
    const float* __restrict__ Wq, const float* __restrict__ Wk, const float* __restrict__ Wv,
    _Float16* __restrict__ Whi, _Float16* __restrict__ Wlo)
{
  int idx = blockIdx.x * 256 + threadIdx.x;  // 3*65536 total
  int mat = idx >> 16;
  int r   = idx & 65535;
  const float* W = (mat == 0) ? Wq : (mat == 1) ? Wk : Wv;
  float v = W[r];
  _Float16 h = (_Float16)v;
  Whi[idx] = h;
  Wlo[idx] = (_Float16)(v - (float)h);
}

// ---------------- kernel A: fused QKV projection ----------------
// Block: 2 waves x 32 tokens. W tiles (16 cols x 256, hi+lo) staged in LDS,
// double-buffered via global_load_lds with XOR chunk swizzle.
// Q stored fp32; K stored fp16 (3-term, then rounded); V fp16 transposed.
__global__ __launch_bounds__(128) void proj_kernel(
    const float* __restrict__ X,
    const float* __restrict__ bq, const float* __restrict__ bk, const float* __restrict__ bv,
    const _Float16* __restrict__ Whi, const _Float16* __restrict__ Wlo,
    float* __restrict__ Qf, _Float16* __restrict__ Kh, _Float16* __restrict__ Vt)
{
  __shared__ _Float16 wl[2][2][16][256];  // [buf][hi/lo][col][feat], swizzled chunks; 32 KB

  const int tid  = threadIdx.x;
  const int w    = tid >> 6;
  const int lane = tid & 63;
  const int l15  = lane & 15;
  const int lg   = lane >> 4;
  const int t0   = blockIdx.x * 64 + w * 32;

  // X A-fragments (32 tokens = 2 row-frags), fp32 split to fp16 hi/lo in regs.
  f16x8 xhi[2][8], xlo[2][8];
  #pragma unroll
  for (int f = 0; f < 2; ++f) {
    const float* src = X + (size_t)(t0 + f * 16 + l15) * C + lg * 8;
    #pragma unroll
    for (int kk = 0; kk < 8; ++kk) {
      float4 a = *(const float4*)(src + kk * 32);
      float4 b = *(const float4*)(src + kk * 32 + 4);
      float v[8] = {a.x, a.y, a.z, a.w, b.x, b.y, b.z, b.w};
      f16x8 h, l;
      #pragma unroll
      for (int j = 0; j < 8; ++j) {
        _Float16 hi = (_Float16)v[j];
        h[j] = hi;
        l[j] = (_Float16)(v[j] - (float)hi);
      }
      xhi[f][kk] = h;
      xlo[f][kk] = l;
    }
  }

  // Staging offsets: g = w*512 + i*64 + lane; col=(g>>5)&15, p=g&31,
  // source chunk c = (p&24)|((p^col)&7).  wave0 -> hi, wave1 -> lo.
  int soff[8];
  #pragma unroll
  for (int i = 0; i < 8; ++i) {
    int g = w * 512 + i * 64 + lane;
    int col = (g >> 5) & 15, p = g & 31;
    int c = (p & 24) | ((p ^ col) & 7);
    soff[i] = col * 256 + c * 8;  // halves within W tile
  }
  const _Float16* wsrc = w ? Wlo : Whi;

  // Compute-read swizzled offsets (bytes within one [16][256] tile).
  int koff[8];
  {
    const int pm = l15 & 7;
    #pragma unroll
    for (int kk = 0; kk < 8; ++kk) {
      int cch = kk * 4 + lg;
      int p = (cch & 24) | ((cch ^ pm) & 7);
      koff[kk] = l15 * 512 + p * 16;  // bytes
    }
  }

  auto stage = [&](int buf, int j) {
    const int rowbase = (j >> 4) * 256 + (j & 15) * 16;
    const _Float16* src0 = wsrc + (size_t)rowbase * 256;
    char* dst0 = (char*)&wl[buf][0][0][0] + (w * 512) * 16;
    #pragma unroll
    for (int i = 0; i < 8; ++i)
      gll16(src0 + soff[i], dst0 + i * 1024);
  };

  stage(0, 0);
  asm volatile("s_waitcnt vmcnt(0)" ::: "memory");
  __syncthreads();

  #pragma unroll 1
  for (int j = 0; j < 48; ++j) {
    const int buf = j & 1;
    const int jn = (j + 1 < 48) ? j + 1 : 0;
    stage(buf ^ 1, jn);

    const char* bh_base = (const char*)&wl[buf][0][0][0];
    const char* bl_base = (const char*)&wl[buf][1][0][0];
    f32x4 acc0 = {0.f, 0.f, 0.f, 0.f};
    f32x4 acc1 = {0.f, 0.f, 0.f, 0.f};
    #pragma unroll
    for (int kk = 0; kk < 8; ++kk) {
      f16x8 bh = *(const f16x8*)(bh_base + koff[kk]);
      f16x8 bl = *(const f16x8*)(bl_base + koff[kk]);
      acc0 = MFMA(xhi[0][kk], bh, acc0);
      acc1 = MFMA(xhi[1][kk], bh, acc1);
      acc0 = MFMA(xlo[0][kk], bh, acc0);
      acc1 = MFMA(xlo[1][kk], bh, acc1);
      acc0 = MFMA(xhi[0][kk], bl, acc0);
      acc1 = MFMA(xhi[1][kk], bl, acc1);
    }

    const int mat = j >> 4;
    const int cg  = (j & 15) * 16 + l15;
    const float bias = ((mat == 0) ? bq : (mat == 1) ? bk : bv)[cg];
    #pragma unroll
    for (int f = 0; f < 2; ++f) {
      f32x4 acc = f ? acc1 : acc0;
      const int tok0 = t0 + f * 16 + lg * 4;
      if (mat == 0) {
        #pragma unroll
        for (int r = 0; r < 4; ++r)
          Qf[(size_t)(tok0 + r) * C + cg] = acc[r] + bias;
      } else if (mat == 1) {
        #pragma unroll
        for (int r = 0; r < 4; ++r)
          Kh[(size_t)(tok0 + r) * C + cg] = (_Float16)(acc[r] + bias);
      } else {
        f16x4 v4;
        #pragma unroll
        for (int r = 0; r < 4; ++r) v4[r] = (_Float16)(acc[r] + bias);
        *(f16x4*)(Vt + (size_t)cg * NTOK + tok0) = v4;
      }
    }

    asm volatile("s_waitcnt vmcnt(0)" ::: "memory");
    __syncthreads();
  }
}

// ---------------- kernel B: flash attention per segment ----------------
// Block = 64 Q-rows (4 waves x 16 rows). 32-key tiles. K double-buffered,
// V single-buffered, async gll staging with counted vmcnt (never 0 in loop).
__global__ __launch_bounds__(256, 3) void attn_kernel(
    const float* __restrict__ Qf, const _Float16* __restrict__ Kh,
    const _Float16* __restrict__ Vt, float* __restrict__ Out)
{
  __shared__ _Float16 k_lds[2][32][256];  // chunk-XOR-swizzled; 32 KB
  __shared__ _Float16 v_lds[256][32];     // source-swizzled slots; 16 KB
  __shared__ _Float16 p_lds[4][16][40];   // wave-private; 5 KB   (total 53 KB)

  const int tid  = threadIdx.x;
  const int w    = tid >> 6;
  const int lane = tid & 63;
  const int l15  = lane & 15;
  const int lg   = lane >> 4;

  // XCD-bijective swizzle: 384 = 8 * 48
  const int bid = blockIdx.x;
  const int qrow0 = ((bid & 7) * 48 + (bid >> 3)) * 64;

  int seg = 0;
  #pragma unroll
  for (int i = 1; i < 8; ++i)
    if (qrow0 >= c_off[i]) seg = i;
  const int s0 = c_off[seg];
  const int nt = (c_off[seg + 1] - s0) >> 5;

  // Q fragments: fp32 load, split hi/lo in registers.
  f16x8 qhi[8], qlo[8];
  {
    const float* src = Qf + (size_t)(qrow0 + w * 16 + l15) * C + lg * 8;
    #pragma unroll
    for (int kk = 0; kk < 8; ++kk) {
      float4 a = *(const float4*)(src + kk * 32);
      float4 b = *(const float4*)(src + kk * 32 + 4);
      float v[8] = {a.x, a.y, a.z, a.w, b.x, b.y, b.z, b.w};
      f16x8 h, l;
      #pragma unroll
      for (int j = 0; j < 8; ++j) {
        _Float16 hi = (_Float16)v[j];
        h[j] = hi;
        l[j] = (_Float16)(v[j] - (float)hi);
      }
      qhi[kk] = h;
      qlo[kk] = l;
    }
  }

  // Staging source offsets (halves), invariant across tiles.
  // K: rows r=key, dest chunk p holds source chunk (p&24)|((p^r)&7).
  // V: linear slot s=d holds dim r=d>>2, source chunk (d&3)^((r>>1)&3).
  int kso[4], vso[4];
  #pragma unroll
  for (int i = 0; i < 4; ++i) {
    int d = w * 256 + i * 64 + lane;
    { int r = d >> 5, p = d & 31;
      int c = (p & 24) | ((p ^ r) & 7);
      kso[i] = r * 256 + c * 8; }
    { int r = d >> 2, pd = d & 3;
      int c = pd ^ ((r >> 1) & 3);
      vso[i] = r * NTOK + c * 8; }
  }

  // Compute-side swizzled K read offsets (bytes within one [32][256] tile).
  int koff[8];
  {
    const int pm = l15 & 7;
    #pragma unroll
    for (int kk = 0; kk < 8; ++kk) {
      int cch = kk * 4 + lg;
      int p = (cch & 24) | ((cch ^ pm) & 7);
      koff[kk] = l15 * 512 + p * 16;  // bytes; row l15+16 is +8192
    }
  }
  // V read: byte(db) = db*1024 + l15*64 + (lg^((l15>>1)&3))*16
  const int vrd = l15 * 64 + ((lg ^ ((l15 >> 1) & 3)) << 4);

  auto stageK = [&](int buf, int kv) {
    const _Float16* ks = Kh + (size_t)(s0 + kv) * C;
    char* kd = (char*)&k_lds[buf][0][0] + w * 4096;
    #pragma unroll
    for (int i = 0; i < 4; ++i) gll16(ks + kso[i], kd + i * 1024);
  };
  auto stageV = [&](int kv) {
    const _Float16* vs = Vt + (s0 + kv);
    char* vd = (char*)&v_lds[0][0] + w * 4096;
    #pragma unroll
    for (int i = 0; i < 4; ++i) gll16(vs + vso[i], vd + i * 1024);
  };

  stageK(0, 0);
  stageV(0);
  asm volatile("s_waitcnt vmcnt(0)" ::: "memory");
  __syncthreads();

  f32x4 o[16];
  #pragma unroll
  for (int db = 0; db < 16; ++db) o[db] = (f32x4){0.f, 0.f, 0.f, 0.f};
  float m_[4] = {-1e30f, -1e30f, -1e30f, -1e30f};
  float ls[4] = {0.f, 0.f, 0.f, 0.f};

  #pragma unroll 1
  for (int t = 0; t < nt; ++t) {
    const int buf = t & 1;
    const int kvn = (t + 1 < nt) ? (t + 1) << 5 : 0;
    stageK(buf ^ 1, kvn);  // K(t+1) in flight across this iteration

    // ---- S = Q K^T : 2-term (qhi + qlo) x khi, fp32 acc ----
    const char* kb = (const char*)&k_lds[buf][0][0];
    f32x4 s0v = {0.f, 0.f, 0.f, 0.f};
    f32x4 s1v = {0.f, 0.f, 0.f, 0.f};
    #pragma unroll
    for (int kk = 0; kk < 8; ++kk) {
      f16x8 b0 = *(const f16x8*)(kb + koff[kk]);
      f16x8 b1 = *(const f16x8*)(kb + koff[kk] + 8192);
      s0v = MFMA(qhi[kk], b0, s0v);
      s1v = MFMA(qhi[kk], b1, s1v);
      s0v = MFMA(qlo[kk], b0, s0v);
      s1v = MFMA(qlo[kk], b1, s1v);
    }

    // ---- online softmax (rows lg*4 + r) ----
    float scale[4];
    #pragma unroll
    for (int r = 0; r < 4; ++r) {
      float mx = fmaxf(s0v[r], s1v[r]);
      mx = fmaxf(mx, __shfl_xor(mx, 1));
      mx = fmaxf(mx, __shfl_xor(mx, 2));
      mx = fmaxf(mx, __shfl_xor(mx, 4));
      mx = fmaxf(mx, __shfl_xor(mx, 8));
      const float mn = fmaxf(m_[r], mx);
      scale[r] = __expf(m_[r] - mn);
      m_[r] = mn;
      const float p0 = __expf(s0v[r] - mn);
      const float p1 = __expf(s1v[r] - mn);
      s0v[r] = p0;
      s1v[r] = p1;
      float rs = p0 + p1;
      rs += __shfl_xor(rs, 1);
      rs += __shfl_xor(rs, 2);
      rs += __shfl_xor(rs, 4);
      rs += __shfl_xor(rs, 8);
      ls[r] = ls[r] * scale[r] + rs;
    }

    // ---- P -> LDS, packed 4B writes (pair columns via shfl_xor(1)) ----
    // even lane (l15=2j): cols (2j, 2j+1); odd lane (l15=2j+1): cols (16+2j, 16+2j+1)
    const int odd = lane & 1;
    const int cbase = odd ? (15 + l15) : l15;
    #pragma unroll
    for (int r = 0; r < 4; ++r) {
      float send = odd ? s0v[r] : s1v[r];
      float tmp = __shfl_xor(send, 1);
      float lov = odd ? tmp : s0v[r];
      float hiv = odd ? s1v[r] : tmp;
      f16x2 pk = {(_Float16)lov, (_Float16)hiv};
      *(f16x2*)&p_lds[w][lg * 4 + r][cbase] = pk;
    }

    // ---- rescale O ----
    #pragma unroll
    for (int db = 0; db < 16; ++db) {
      #pragma unroll
      for (int r = 0; r < 4; ++r) o[db][r] *= scale[r];
    }

    // ---- drain V(t) (K(t+1) may stay in flight), then O += P V ----
    asm volatile("s_waitcnt vmcnt(4)" ::: "memory");
    f16x8 pfrag = *(const f16x8*)&p_lds[w][l15][lg * 8];
    const char* vb = (const char*)&v_lds[0][0] + vrd;
    #pragma unroll
    for (int db = 0; db < 16; ++db) {
      f16x8 vfrag = *(const f16x8*)(vb + db * 1024);
      o[db] = MFMA(pfrag, vfrag, o[db]);
    }

    __syncthreads();            // all waves done reading v_lds
    stageV(kvn);                // V(t+1) in flight
    asm volatile("s_waitcnt vmcnt(4)" ::: "memory");  // K(t+1) done
    __syncthreads();
  }

  // ---- epilogue ----
  #pragma unroll
  for (int r = 0; r < 4; ++r) ls[r] = 1.f / ls[r];
  const int orow = qrow0 + w * 16 + lg * 4;
  #pragma unroll
  for (int db = 0; db < 16; ++db) {
    #pragma unroll
    for (int r = 0; r < 4; ++r) {
      Out[(size_t)(orow + r) * C + db * 16 + l15] = o[db][r] * ls[r];
    }
  }
}

extern "C" void kernel_launch(void* const* d_in, const int* in_sizes, int n_in,
                              void* d_out, int out_size, void* d_ws, size_t ws_size,
                              hipStream_t stream)
{
  const float* X  = (const float*)d_in[0];
  // d_in[1] = indices (unused by the reference math)
  const float* Wq = (const float*)d_in[2];
  const float* bq = (const float*)d_in[3];
  const float* Wk = (const float*)d_in[4];
  const float* bk = (const float*)d_in[5];
  const float* Wv = (const float*)d_in[6];
  const float* bv = (const float*)d_in[7];
  float* Out = (float*)d_out;

  // workspace: Qf fp32 (25.2MB) | Kh fp16 (12.6) | Vt fp16 (12.6) | Whi | Wlo
  const size_t SZ = (size_t)NTOK * C;
  float*    Qf  = (float*)d_ws;
  _Float16* Kh  = (_Float16*)(Qf + SZ);
  _Float16* Vt  = Kh + SZ;
  _Float16* Whi = Vt + SZ;
  _Float16* Wlo = Whi + (size_t)3 * 65536;

  hipLaunchKernelGGL(wsplit_kernel, dim3(768), dim3(256), 0, stream,
                     Wq, Wk, Wv, Whi, Wlo);
  hipLaunchKernelGGL(proj_kernel, dim3(384), dim3(128), 0, stream,
                     X, bq, bk, bv, Whi, Wlo, Qf, Kh, Vt);
  hipLaunchKernelGGL(attn_kernel, dim3(384), dim3(256), 0, stream,
                     Qf, Kh, Vt, Out);
}

// Round 6
// 356.227 us; speedup vs baseline: 1.7703x; 1.5929x over previous
//
#include <hip/hip_runtime.h>

// SP_Attentation v4.1: swapped QK^T (lane-local softmax), raw s_barrier +
// counted vmcnt double-buffered K/V staging, defer-rescale, pipelined proj.
// (v4 + fix: proj staged tile index used &47 on a non-pow2 modulus, which
//  dropped bit 4 and made K use Wq's weight tiles.)

typedef _Float16 f16x8 __attribute__((ext_vector_type(8)));
typedef _Float16 f16x4 __attribute__((ext_vector_type(4)));
typedef _Float16 f16x2 __attribute__((ext_vector_type(2)));
typedef float    f32x4 __attribute__((ext_vector_type(4)));
typedef unsigned int u32;

#define MFMA(a,b,c) __builtin_amdgcn_mfma_f32_16x16x32_f16((a),(b),(c),0,0,0)

typedef __attribute__((address_space(1))) const u32 gu32_t;
typedef __attribute__((address_space(3))) u32 lu32_t;

__device__ __forceinline__ void gll16(const void* g, void* l) {
  __builtin_amdgcn_global_load_lds((gu32_t*)g, (lu32_t*)l, 16, 0, 0);
}
#define VMCNT(n) asm volatile("s_waitcnt vmcnt(" #n ")" ::: "memory")
#define BAR() __builtin_amdgcn_s_barrier()

__constant__ int c_off[9] = {0, 3072, 7168, 9216, 12800, 15360, 19456, 22528, 24576};

static constexpr int NTOK = 24576;
static constexpr int C    = 256;

// ---------------- kernel A0: split weights fp32 -> fp16 hi/lo ----------------
__global__ __launch_bounds__(256) void wsplit_kernel(
    const float* __restrict__ Wq, const float* __restrict__ Wk, const float* __restrict__ Wv,
    _Float16* __restrict__ Whi, _Float16* __restrict__ Wlo)
{
  int idx = blockIdx.x * 256 + threadIdx.x;  // 3*65536 total
  int mat = idx >> 16;
  int r   = idx & 65535;
  const float* W = (mat == 0) ? Wq : (mat == 1) ? Wk : Wv;
  float v = W[r];
  _Float16 h = (_Float16)v;
  Whi[idx] = h;
  Wlo[idx] = (_Float16)(v - (float)h);
}

// ---------------- kernel A: fused QKV projection ----------------
// Block: 4 waves x 16 tokens = 64 tokens. W tiles (16 cols x 256, hi+lo = 16KB)
// staged via global_load_lds, 2 tiles ahead, raw barriers + counted vmcnt.
__global__ __launch_bounds__(256) void proj_kernel(
    const float* __restrict__ X,
    const float* __restrict__ bq, const float* __restrict__ bk, const float* __restrict__ bv,
    const _Float16* __restrict__ Whi, const _Float16* __restrict__ Wlo,
    float* __restrict__ Qf, _Float16* __restrict__ Kh, _Float16* __restrict__ Vt)
{
  __shared__ _Float16 wl[2][2][16][256];  // [buf][hi/lo][col][feat], swizzled; 32 KB

  const int tid  = threadIdx.x;
  const int w    = tid >> 6;
  const int lane = tid & 63;
  const int l15  = lane & 15;
  const int lg   = lane >> 4;
  const int t0   = blockIdx.x * 64 + w * 16;

  // X A-fragment (16 tokens), fp32 split to fp16 hi/lo in regs.
  f16x8 xhi[8], xlo[8];
  {
    const float* src = X + (size_t)(t0 + l15) * C + lg * 8;
    #pragma unroll
    for (int kk = 0; kk < 8; ++kk) {
      float4 a = *(const float4*)(src + kk * 32);
      float4 b = *(const float4*)(src + kk * 32 + 4);
      float v[8] = {a.x, a.y, a.z, a.w, b.x, b.y, b.z, b.w};
      f16x8 h, l;
      #pragma unroll
      for (int j = 0; j < 8; ++j) {
        _Float16 hi = (_Float16)v[j];
        h[j] = hi;
        l[j] = (_Float16)(v[j] - (float)hi);
      }
      xhi[kk] = h;
      xlo[kk] = l;
    }
  }

  // Staging: 1024 16B-slots per tile (hi 512 + lo 512); 4 per lane.
  // slot g: h=g>>9, col=(g>>5)&15, p=g&31; src chunk c=(p&24)|((p^col)&7).
  int soff[4];
  const _Float16* sbase[4];
  #pragma unroll
  for (int i = 0; i < 4; ++i) {
    int g = w * 256 + i * 64 + lane;
    int col = (g >> 5) & 15, p = g & 31;
    int c = (p & 24) | ((p ^ col) & 7);
    soff[i] = col * 256 + c * 8;
    sbase[i] = (g >> 9) ? Wlo : Whi;
  }

  // Compute-read swizzled offsets (bytes within one [16][256] half-tile).
  int koff[8];
  {
    const int pm = l15 & 7;
    #pragma unroll
    for (int kk = 0; kk < 8; ++kk) {
      int cch = kk * 4 + lg;
      int p = (cch & 24) | ((cch ^ pm) & 7);
      koff[kk] = l15 * 512 + p * 16;  // bytes
    }
  }

  auto stage = [&](int buf, int j) {
    const int rowbase = (j >> 4) * 256 + (j & 15) * 16;
    char* dst = (char*)&wl[buf][0][0][0] + (w * 256) * 16;
    #pragma unroll
    for (int i = 0; i < 4; ++i)
      gll16(sbase[i] + (size_t)rowbase * 256 + soff[i], dst + i * 1024);
  };

  stage(0, 0);
  stage(1, 1);
  VMCNT(4);   // tile 0 landed (tile 1 in flight)
  BAR();

  #pragma unroll 1
  for (int j = 0; j < 48; ++j) {
    const int buf = j & 1;
    const char* bh_base = (const char*)&wl[buf][0][0][0];
    const char* bl_base = (const char*)&wl[buf][1][0][0];
    f32x4 acc = {0.f, 0.f, 0.f, 0.f};
    const int mat = j >> 4;
    if (mat < 2) {
      #pragma unroll
      for (int kk = 0; kk < 8; ++kk) {
        f16x8 bh = *(const f16x8*)(bh_base + koff[kk]);
        f16x8 bl = *(const f16x8*)(bl_base + koff[kk]);
        acc = MFMA(xhi[kk], bh, acc);
        acc = MFMA(xlo[kk], bh, acc);
        acc = MFMA(xhi[kk], bl, acc);
      }
    } else {
      #pragma unroll
      for (int kk = 0; kk < 8; ++kk) {
        f16x8 bh = *(const f16x8*)(bh_base + koff[kk]);
        acc = MFMA(xhi[kk], bh, acc);
      }
    }

    const int cg = (j & 15) * 16 + l15;
    const float bias = ((mat == 0) ? bq : (mat == 1) ? bk : bv)[cg];
    const int tok0 = t0 + lg * 4;
    if (mat == 0) {
      #pragma unroll
      for (int r = 0; r < 4; ++r)
        Qf[(size_t)(tok0 + r) * C + cg] = acc[r] + bias;
    } else if (mat == 1) {
      #pragma unroll
      for (int r = 0; r < 4; ++r)
        Kh[(size_t)(tok0 + r) * C + cg] = (_Float16)(acc[r] + bias);
    } else {
      f16x4 v4;
      #pragma unroll
      for (int r = 0; r < 4; ++r) v4[r] = (_Float16)(acc[r] + bias);
      *(f16x4*)(Vt + (size_t)cg * NTOK + tok0) = v4;
    }

    BAR();                      // all waves done reading buf
    int jn = j + 2;             // FIX: true mod-48 (was (j+2)&47, drops bit 4)
    if (jn >= 48) jn -= 48;     // (tail stages are dummies, never consumed)
    stage(buf, jn);
    VMCNT(4);                   // tile j+1 landed; j+2 in flight
    BAR();
  }
}

// ---------------- kernel B: flash attention per segment ----------------
// Block = 64 Q-rows (4 waves x 16 rows). 32-key tiles, K+V double-buffered,
// async gll staging, raw barriers + counted vmcnt, swapped-QK lane-local softmax.
__global__ __launch_bounds__(256) void attn_kernel(
    const float* __restrict__ Qf, const _Float16* __restrict__ Kh,
    const _Float16* __restrict__ Vt, float* __restrict__ Out)
{
  __shared__ _Float16 k_lds[2][32][256];  // chunk-XOR-swizzled; 32 KB
  __shared__ _Float16 v_lds[2][256][32];  // source-swizzled slots; 32 KB
  __shared__ _Float16 p_lds[4][16][40];   // wave-private; 5 KB   (total 69 KB)

  const int tid  = threadIdx.x;
  const int w    = tid >> 6;
  const int lane = tid & 63;
  const int l15  = lane & 15;
  const int lg   = lane >> 4;

  // XCD-bijective swizzle: 384 = 8 * 48
  const int bid = blockIdx.x;
  const int qrow0 = ((bid & 7) * 48 + (bid >> 3)) * 64;

  int seg = 0;
  #pragma unroll
  for (int i = 1; i < 8; ++i)
    if (qrow0 >= c_off[i]) seg = i;
  const int s0 = c_off[seg];
  const int nt = (c_off[seg + 1] - s0) >> 5;

  // Q fragments (B-operand: col=l15=qrow): fp32 load, split hi/lo in regs.
  f16x8 qhi[8], qlo[8];
  {
    const float* src = Qf + (size_t)(qrow0 + w * 16 + l15) * C + lg * 8;
    #pragma unroll
    for (int kk = 0; kk < 8; ++kk) {
      float4 a = *(const float4*)(src + kk * 32);
      float4 b = *(const float4*)(src + kk * 32 + 4);
      float v[8] = {a.x, a.y, a.z, a.w, b.x, b.y, b.z, b.w};
      f16x8 h, l;
      #pragma unroll
      for (int j = 0; j < 8; ++j) {
        _Float16 hi = (_Float16)v[j];
        h[j] = hi;
        l[j] = (_Float16)(v[j] - (float)hi);
      }
      qhi[kk] = h;
      qlo[kk] = l;
    }
  }

  // Staging source offsets (halves), invariant across tiles.
  int kso[4], vso[4];
  #pragma unroll
  for (int i = 0; i < 4; ++i) {
    int d = w * 256 + i * 64 + lane;
    { int r = d >> 5, p = d & 31;
      int c = (p & 24) | ((p ^ r) & 7);
      kso[i] = r * 256 + c * 8; }
    { int r = d >> 2, pd = d & 3;
      int c = pd ^ ((r >> 1) & 3);
      vso[i] = r * NTOK + c * 8; }
  }

  // K read offsets (A-operand rows=keys): swizzled, bytes in [32][256] tile.
  int koff[8];
  {
    const int pm = l15 & 7;
    #pragma unroll
    for (int kk = 0; kk < 8; ++kk) {
      int cch = kk * 4 + lg;
      int p = (cch & 24) | ((cch ^ pm) & 7);
      koff[kk] = l15 * 512 + p * 16;  // row l15; row l15+16 is +8192
    }
  }
  // V read: byte(db) = db*1024 + l15*64 + (lg^((l15>>1)&3))*16
  const int vrd = l15 * 64 + ((lg ^ ((l15 >> 1) & 3)) << 4);

  auto stageK = [&](int buf, int kv) {
    const _Float16* ks = Kh + (size_t)(s0 + kv) * C;
    char* kd = (char*)&k_lds[buf][0][0] + w * 4096;
    #pragma unroll
    for (int i = 0; i < 4; ++i) gll16(ks + kso[i], kd + i * 1024);
  };
  auto stageV = [&](int buf, int kv) {
    const _Float16* vs = Vt + (s0 + kv);
    char* vd = (char*)&v_lds[buf][0][0] + w * 4096;
    #pragma unroll
    for (int i = 0; i < 4; ++i) gll16(vs + vso[i], vd + i * 1024);
  };

  stageK(0, 0);
  stageV(0, 0);
  VMCNT(0);
  BAR();

  f32x4 o[16];
  #pragma unroll
  for (int db = 0; db < 16; ++db) o[db] = (f32x4){0.f, 0.f, 0.f, 0.f};
  float m_ = -1e30f;   // running max of q-row l15 (replicated over lg)
  float ls = 0.f;      // running denom of q-row l15

  #pragma unroll 1
  for (int t = 0; t < nt; ++t) {
    const int buf = t & 1;
    const int kvn = (t + 1 < nt) ? (t + 1) << 5 : 0;
    stageK(buf ^ 1, kvn);   // K older than V in vmcnt queue
    stageV(buf ^ 1, kvn);

    // ---- S^T = K Q^T (swapped): lane holds keys {lg*4+r, 16+lg*4+r} of row l15
    const char* kb = (const char*)&k_lds[buf][0][0];
    f32x4 s0v = {0.f, 0.f, 0.f, 0.f};
    f32x4 s1v = {0.f, 0.f, 0.f, 0.f};
    #pragma unroll
    for (int kk = 0; kk < 8; ++kk) {
      f16x8 b0 = *(const f16x8*)(kb + koff[kk]);
      f16x8 b1 = *(const f16x8*)(kb + koff[kk] + 8192);
      s0v = MFMA(b0, qhi[kk], s0v);
      s1v = MFMA(b1, qhi[kk], s1v);
      s0v = MFMA(b0, qlo[kk], s0v);
      s1v = MFMA(b1, qlo[kk], s1v);
    }

    // ---- lane-local online softmax for q-row l15 ----
    float pmax = fmaxf(fmaxf(fmaxf(s0v[0], s0v[1]), fmaxf(s0v[2], s0v[3])),
                       fmaxf(fmaxf(s1v[0], s1v[1]), fmaxf(s1v[2], s1v[3])));
    pmax = fmaxf(pmax, __shfl_xor(pmax, 16));
    pmax = fmaxf(pmax, __shfl_xor(pmax, 32));

    const bool need = !__all(pmax <= m_ + 8.f);   // defer-rescale (T13)
    float scale = 1.f;
    if (need) {
      const float mn = fmaxf(m_, pmax);
      scale = __expf(m_ - mn);
      m_ = mn;
    }
    #pragma unroll
    for (int r = 0; r < 4; ++r) {
      s0v[r] = __expf(s0v[r] - m_);
      s1v[r] = __expf(s1v[r] - m_);
    }
    float rs = (s0v[0] + s0v[1]) + (s0v[2] + s0v[3]) +
               (s1v[0] + s1v[1]) + (s1v[2] + s1v[3]);
    rs += __shfl_xor(rs, 16);
    rs += __shfl_xor(rs, 32);
    ls = ls * scale + rs;

    // ---- P -> p_lds (wave-private): row l15, keys lg*4.. and 16+lg*4.. ----
    {
      f16x2 a = {(_Float16)s0v[0], (_Float16)s0v[1]};
      f16x2 b = {(_Float16)s0v[2], (_Float16)s0v[3]};
      f16x2 c = {(_Float16)s1v[0], (_Float16)s1v[1]};
      f16x2 d = {(_Float16)s1v[2], (_Float16)s1v[3]};
      *(f16x2*)&p_lds[w][l15][lg * 4]      = a;
      *(f16x2*)&p_lds[w][l15][lg * 4 + 2]  = b;
      *(f16x2*)&p_lds[w][l15][16 + lg * 4]     = c;
      *(f16x2*)&p_lds[w][l15][16 + lg * 4 + 2] = d;
    }

    // ---- rescale O (only when max moved; o rows are qrows lg*4+r) ----
    if (need) {
      float s4[4];
      #pragma unroll
      for (int r = 0; r < 4; ++r) s4[r] = __shfl(scale, lg * 4 + r);
      #pragma unroll
      for (int db = 0; db < 16; ++db) {
        #pragma unroll
        for (int r = 0; r < 4; ++r) o[db][r] *= s4[r];
      }
    }

    VMCNT(8);   // V(t) landed (K(t+1),V(t+1) still in flight)
    BAR();      // ... in ALL waves

    // ---- O += P V ----
    f16x8 pfrag = *(const f16x8*)&p_lds[w][l15][lg * 8];
    const char* vb = (const char*)&v_lds[buf][0][0] + vrd;
    #pragma unroll
    for (int db = 0; db < 16; ++db) {
      f16x8 vfrag = *(const f16x8*)(vb + db * 1024);
      o[db] = MFMA(pfrag, vfrag, o[db]);
    }

    VMCNT(4);   // K(t+1) landed (V(t+1) still in flight)
    BAR();
  }

  // ---- epilogue: normalize and store fp32 ----
  float l4[4];
  #pragma unroll
  for (int r = 0; r < 4; ++r) l4[r] = 1.f / __shfl(ls, lg * 4 + r);
  const int orow = qrow0 + w * 16 + lg * 4;
  #pragma unroll
  for (int db = 0; db < 16; ++db) {
    #pragma unroll
    for (int r = 0; r < 4; ++r) {
      Out[(size_t)(orow + r) * C + db * 16 + l15] = o[db][r] * l4[r];
    }
  }
}

extern "C" void kernel_launch(void* const* d_in, const int* in_sizes, int n_in,
                              void* d_out, int out_size, void* d_ws, size_t ws_size,
                              hipStream_t stream)
{
  const float* X  = (const float*)d_in[0];
  // d_in[1] = indices (unused by the reference math)
  const float* Wq = (const float*)d_in[2];
  const float* bq = (const float*)d_in[3];
  const float* Wk = (const float*)d_in[4];
  const float* bk = (const float*)d_in[5];
  const float* Wv = (const float*)d_in[6];
  const float* bv = (const float*)d_in[7];
  float* Out = (float*)d_out;

  // workspace: Qf fp32 (25.2MB) | Kh fp16 (12.6) | Vt fp16 (12.6) | Whi | Wlo
  const size_t SZ = (size_t)NTOK * C;
  float*    Qf  = (float*)d_ws;
  _Float16* Kh  = (_Float16*)(Qf + SZ);
  _Float16* Vt  = Kh + SZ;
  _Float16* Whi = Vt + SZ;
  _Float16* Wlo = Whi + (size_t)3 * 65536;

  hipLaunchKernelGGL(wsplit_kernel, dim3(768), dim3(256), 0, stream,
                     Wq, Wk, Wv, Whi, Wlo);
  hipLaunchKernelGGL(proj_kernel, dim3(384), dim3(256), 0, stream,
                     X, bq, bk, bv, Whi, Wlo, Qf, Kh, Vt);
  hipLaunchKernelGGL(attn_kernel, dim3(384), dim3(256), 0, stream,
                     Qf, Kh, Vt, Out);
}